// Round 4
// baseline (129.830 us; speedup 1.0000x reference)
//
#include <hip/hip_runtime.h>
#include <hip/hip_fp16.h>
#include <hip/hip_cooperative_groups.h>

namespace cg = cooperative_groups;

#define NROWS 512
#define BHALF 256
#define DIM   512
#define TILE  64
#define DCHUNK 64
#define NCHUNK 8
#define NN (NROWS * NROWS)
#define SOFF (8 * NN)   // float offset of per-block distance-sum partials
// ws layout:
//   bytes  [0 .. 8*NN*4)        : packed half2(l2_partial, l1_partial), one NN-buffer per d-chunk
//   floats [SOFF .. SOFF+1024)  : per-block sum partials (512 S2, then 512 S1)

#define ACC(A, Bb, IV, JV)                                    \
    {                                                         \
        const float d_ = (IV) - (JV);                         \
        a2[A][Bb] = fmaf(d_, d_, a2[A][Bb]);                  \
        a1[A][Bb] += fabsf(d_);                               \
    }

#define STEP(DD)                                              \
    {                                                         \
        const float4 ivv = *(const float4*)&ai[DD][ty4];      \
        const float4 jvv = *(const float4*)&aj[DD][tx4];      \
        ACC(0, 0, ivv.x, jvv.x) ACC(0, 1, ivv.x, jvv.y)       \
        ACC(0, 2, ivv.x, jvv.z) ACC(0, 3, ivv.x, jvv.w)       \
        ACC(1, 0, ivv.y, jvv.x) ACC(1, 1, ivv.y, jvv.y)       \
        ACC(1, 2, ivv.y, jvv.z) ACC(1, 3, ivv.y, jvv.w)       \
        ACC(2, 0, ivv.z, jvv.x) ACC(2, 1, ivv.z, jvv.y)       \
        ACC(2, 2, ivv.z, jvv.z) ACC(2, 3, ivv.z, jvv.w)       \
        ACC(3, 0, ivv.w, jvv.x) ACC(3, 1, ivv.w, jvv.y)       \
        ACC(3, 2, ivv.w, jvv.z) ACC(3, 3, ivv.w, jvv.w)       \
    }

__device__ __forceinline__ unsigned int pack_h2(float l2v, float l1v) {
    const __half2 h = __halves2half2(__float2half_rn(l2v), __float2half_rn(l1v));
    union { __half2 h; unsigned int u; } c; c.h = h;
    return c.u;
}

__global__ __launch_bounds__(256) void k_fused(const float* __restrict__ src,
                                               const float* __restrict__ tgt,
                                               float* __restrict__ ws,
                                               float* __restrict__ out)
{
    __shared__ float ai[DCHUNK][TILE];   // 16 KB, transposed [d][row]
    __shared__ float aj[DCHUNK][TILE];   // 16 KB

    const int tj = blockIdx.x;   // 0..7
    const int ti = blockIdx.y;   // 0..7
    const int dc = blockIdx.z;   // 0..7
    const int t  = threadIdx.x;

    // zero the output before the grid sync (poisoned 0xAA by harness)
    if (t == 0 && tj == 0 && ti == 0 && dc == 0) out[0] = 0.0f;

    // ================= phase 1: distances =================
    {
        const int r  = t & 63;
        const int dg = t >> 6;
        const int gi = ti * TILE + r;
        const int gj = tj * TILE + r;
        const float* prow_i = (gi < BHALF ? src + (size_t)gi * DIM
                                          : tgt + (size_t)(gi - BHALF) * DIM) + dc * DCHUNK;
        const float* prow_j = (gj < BHALF ? src + (size_t)gj * DIM
                                          : tgt + (size_t)(gj - BHALF) * DIM) + dc * DCHUNK;
#pragma unroll
        for (int k = 0; k < 4; ++k) {
            const int d4 = dg * 4 + k;
            const float4 vi = *(const float4*)(prow_i + d4 * 4);
            const float4 vj = *(const float4*)(prow_j + d4 * 4);
            ai[d4 * 4 + 0][r] = vi.x; ai[d4 * 4 + 1][r] = vi.y;
            ai[d4 * 4 + 2][r] = vi.z; ai[d4 * 4 + 3][r] = vi.w;
            aj[d4 * 4 + 0][r] = vj.x; aj[d4 * 4 + 1][r] = vj.y;
            aj[d4 * 4 + 2][r] = vj.z; aj[d4 * 4 + 3][r] = vj.w;
        }
    }
    __syncthreads();

    const int tx  = t & 15;
    const int ty  = t >> 4;
    const int tx4 = tx * 4;
    const int ty4 = ty * 4;

    float a2[4][4], a1[4][4];
#pragma unroll
    for (int a = 0; a < 4; ++a)
#pragma unroll
        for (int b = 0; b < 4; ++b) { a2[a][b] = 0.f; a1[a][b] = 0.f; }

#pragma unroll 4
    for (int d = 0; d < DCHUNK; d += 2) {
        STEP(d)
        STEP(d + 1)
    }

    // packed half2(l2,l1) partial tiles: 4 B/pair/chunk -> 8 MB total
    unsigned int* part = (unsigned int*)ws + (size_t)dc * NN;
    const int gj0 = tj * TILE + tx4;
#pragma unroll
    for (int a = 0; a < 4; ++a) {
        const int gi = ti * TILE + ty4 + a;
        const uint4 pk = make_uint4(pack_h2(a2[a][0], a1[a][0]),
                                    pack_h2(a2[a][1], a1[a][1]),
                                    pack_h2(a2[a][2], a1[a][2]),
                                    pack_h2(a2[a][3], a1[a][3]));
        *(uint4*)&part[(size_t)gi * NROWS + gj0] = pk;
    }

    // block distance-sums (exact fp32) -> dedicated slots
    {
        float s2 = 0.f, s1 = 0.f;
#pragma unroll
        for (int a = 0; a < 4; ++a)
#pragma unroll
            for (int b = 0; b < 4; ++b) { s2 += a2[a][b]; s1 += a1[a][b]; }
#pragma unroll
        for (int off = 32; off > 0; off >>= 1) {
            s2 += __shfl_down(s2, off);
            s1 += __shfl_down(s1, off);
        }
        __syncthreads();
        float* red = &ai[0][0];
        const int wave = t >> 6;
        if ((t & 63) == 0) { red[wave * 2] = s2; red[wave * 2 + 1] = s1; }
        __syncthreads();
        if (t == 0) {
            const int bid = (dc * 8 + ti) * 8 + tj;
            ws[SOFF + bid]       = red[0] + red[2] + red[4] + red[6];
            ws[SOFF + 512 + bid] = red[1] + red[3] + red[5] + red[7];
        }
    }

    // ================= grid-wide barrier =================
    cg::this_grid().sync();

    // ================= phase 2: kernels + signed mean =================
    __shared__ float sred[8];

    // every block redundantly reduces the 1024 sum partials (L2/L3 broadcast)
    float sp2 = ws[SOFF + t] + ws[SOFF + 256 + t];
    float sp1 = ws[SOFF + 512 + t] + ws[SOFF + 768 + t];
#pragma unroll
    for (int off = 32; off > 0; off >>= 1) {
        sp2 += __shfl_down(sp2, off);
        sp1 += __shfl_down(sp1, off);
    }
    if ((t & 63) == 0) { sred[(t >> 6) * 2] = sp2; sred[(t >> 6) * 2 + 1] = sp1; }
    __syncthreads();
    const float S2 = sred[0] + sred[2] + sred[4] + sred[6];
    const float S1 = sred[1] + sred[3] + sred[5] + sred[7];
    // bw = S/(N^2-N)/100 ; factor_t = (N^2-N)*100/S * 0.1^t
    const float r2 = 26163200.0f / S2;   // 512*511*100
    const float r1 = 26163200.0f / S1;

    const int b = (blockIdx.z * 8 + blockIdx.y) * 8 + blockIdx.x;  // 0..511
    const int p0 = (b * 256 + t) * 2;                              // even pair index
    const unsigned int* partr = (const unsigned int*)ws;

    float l2a = 0.f, l1a = 0.f, l2b = 0.f, l1b = 0.f;
#pragma unroll
    for (int c = 0; c < NCHUNK; ++c) {
        const uint2 w2 = *(const uint2*)&partr[(size_t)c * NN + p0];
        union { unsigned int u; __half2 h; } ca, cb;
        ca.u = w2.x; cb.u = w2.y;
        const float2 fa = __half22float2(ca.h);
        const float2 fb = __half22float2(cb.h);
        l2a += fa.x; l1a += fa.y;
        l2b += fb.x; l1b += fb.y;
    }

    float kv = 0.f;
    {
        float f2 = r2, f1 = r1;
#pragma unroll
        for (int tt = 0; tt < 5; ++tt) {
            kv += __expf(-l2a * f2) + __expf(-l1a * f1)
                + __expf(-l2b * f2) + __expf(-l1b * f1);
            f2 *= 0.1f;
            f1 *= 0.1f;
        }
    }
    // sign is uniform across the dwordx2 pair (p0 even -> bit8(j) identical)
    const int i = p0 >> 9;
    const int j = p0 & 511;
    float acc = ((((i ^ j) & BHALF) == 0) ? kv : -kv);

#pragma unroll
    for (int off = 32; off > 0; off >>= 1) acc += __shfl_down(acc, off);

    __syncthreads();
    if ((t & 63) == 0) sred[t >> 6] = acc;
    __syncthreads();
    if (t == 0) {
        const float s = sred[0] + sred[1] + sred[2] + sred[3];
        atomicAdd(out, s * (1.0f / 65536.0f));
    }
}

extern "C" void kernel_launch(void* const* d_in, const int* in_sizes, int n_in,
                              void* d_out, int out_size, void* d_ws, size_t ws_size,
                              hipStream_t stream)
{
    const float* src = (const float*)d_in[0];
    const float* tgt = (const float*)d_in[1];
    float* ws  = (float*)d_ws;
    float* out = (float*)d_out;

    void* args[] = { (void*)&src, (void*)&tgt, (void*)&ws, (void*)&out };
    hipLaunchCooperativeKernel((const void*)k_fused, dim3(8, 8, 8), dim3(256),
                               args, 0, stream);
}

// Round 5
// 81.213 us; speedup vs baseline: 1.5986x; 1.5986x over previous
//
#include <hip/hip_runtime.h>
#include <hip/hip_fp16.h>

#define NROWS 512
#define BHALF 256
#define DIM   512
#define TILE  64
#define DCHUNK 64
#define NCHUNK 8
#define NN (NROWS * NROWS)
#define SOFF (8 * NN)   // float offset of per-block distance-sum partials
// ws layout:
//   bytes  [0 .. 8*NN*4)        : packed half2(l2_partial, l1_partial), one NN-buffer per d-chunk
//   floats [SOFF .. SOFF+1024)  : per-block sum partials (512 S2, then 512 S1)

#define ACC(A, Bb, IV, JV)                                    \
    {                                                         \
        const float d_ = (IV) - (JV);                         \
        a2[A][Bb] = fmaf(d_, d_, a2[A][Bb]);                  \
        a1[A][Bb] += fabsf(d_);                               \
    }

#define STEP(DD)                                              \
    {                                                         \
        const float4 ivv = *(const float4*)&ai[DD][ty4];      \
        const float4 jvv = *(const float4*)&aj[DD][tx4];      \
        ACC(0, 0, ivv.x, jvv.x) ACC(0, 1, ivv.x, jvv.y)       \
        ACC(0, 2, ivv.x, jvv.z) ACC(0, 3, ivv.x, jvv.w)       \
        ACC(1, 0, ivv.y, jvv.x) ACC(1, 1, ivv.y, jvv.y)       \
        ACC(1, 2, ivv.y, jvv.z) ACC(1, 3, ivv.y, jvv.w)       \
        ACC(2, 0, ivv.z, jvv.x) ACC(2, 1, ivv.z, jvv.y)       \
        ACC(2, 2, ivv.z, jvv.z) ACC(2, 3, ivv.z, jvv.w)       \
        ACC(3, 0, ivv.w, jvv.x) ACC(3, 1, ivv.w, jvv.y)       \
        ACC(3, 2, ivv.w, jvv.z) ACC(3, 3, ivv.w, jvv.w)       \
    }

__device__ __forceinline__ unsigned int pack_h2(float l2v, float l1v) {
    const __half2 h = __halves2half2(__float2half_rn(l2v), __float2half_rn(l1v));
    union { __half2 h; unsigned int u; } c; c.h = h;
    return c.u;
}

__global__ __launch_bounds__(256) void k_dist(const float* __restrict__ src,
                                              const float* __restrict__ tgt,
                                              float* __restrict__ ws,
                                              float* __restrict__ out)
{
    __shared__ float ai[DCHUNK][TILE];   // 16 KB, transposed [d][row]
    __shared__ float aj[DCHUNK][TILE];   // 16 KB

    const int tj = blockIdx.x;   // 0..7
    const int ti = blockIdx.y;   // 0..7
    const int dc = blockIdx.z;   // 0..7
    const int t  = threadIdx.x;

    // fold the out-zeroing into this kernel (stream order: before k_mmd's atomics)
    if (t == 0 && tj == 0 && ti == 0 && dc == 0) out[0] = 0.0f;

    // ---- stage global -> LDS (transposed; 2-way bank aliasing = free) ----
    {
        const int r  = t & 63;
        const int dg = t >> 6;
        const int gi = ti * TILE + r;
        const int gj = tj * TILE + r;
        const float* prow_i = (gi < BHALF ? src + (size_t)gi * DIM
                                          : tgt + (size_t)(gi - BHALF) * DIM) + dc * DCHUNK;
        const float* prow_j = (gj < BHALF ? src + (size_t)gj * DIM
                                          : tgt + (size_t)(gj - BHALF) * DIM) + dc * DCHUNK;
#pragma unroll
        for (int k = 0; k < 4; ++k) {
            const int d4 = dg * 4 + k;
            const float4 vi = *(const float4*)(prow_i + d4 * 4);
            const float4 vj = *(const float4*)(prow_j + d4 * 4);
            ai[d4 * 4 + 0][r] = vi.x; ai[d4 * 4 + 1][r] = vi.y;
            ai[d4 * 4 + 2][r] = vi.z; ai[d4 * 4 + 3][r] = vi.w;
            aj[d4 * 4 + 0][r] = vj.x; aj[d4 * 4 + 1][r] = vj.y;
            aj[d4 * 4 + 2][r] = vj.z; aj[d4 * 4 + 3][r] = vj.w;
        }
    }
    __syncthreads();

    const int tx  = t & 15;
    const int ty  = t >> 4;
    const int tx4 = tx * 4;
    const int ty4 = ty * 4;

    float a2[4][4], a1[4][4];
#pragma unroll
    for (int a = 0; a < 4; ++a)
#pragma unroll
        for (int b = 0; b < 4; ++b) { a2[a][b] = 0.f; a1[a][b] = 0.f; }

#pragma unroll 4
    for (int d = 0; d < DCHUNK; d += 2) {
        STEP(d)
        STEP(d + 1)
    }

    // ---- store packed half2(l2,l1) partial tiles: 4 B/pair/chunk -> 8 MB total ----
    unsigned int* part = (unsigned int*)ws + (size_t)dc * NN;
    const int gj0 = tj * TILE + tx4;
#pragma unroll
    for (int a = 0; a < 4; ++a) {
        const int gi = ti * TILE + ty4 + a;
        const uint4 pk = make_uint4(pack_h2(a2[a][0], a1[a][0]),
                                    pack_h2(a2[a][1], a1[a][1]),
                                    pack_h2(a2[a][2], a1[a][2]),
                                    pack_h2(a2[a][3], a1[a][3]));
        *(uint4*)&part[(size_t)gi * NROWS + gj0] = pk;
    }

    // ---- block distance-sums (exact fp32) -> dedicated slots ----
    float s2 = 0.f, s1 = 0.f;
#pragma unroll
    for (int a = 0; a < 4; ++a)
#pragma unroll
        for (int b = 0; b < 4; ++b) { s2 += a2[a][b]; s1 += a1[a][b]; }
#pragma unroll
    for (int off = 32; off > 0; off >>= 1) {
        s2 += __shfl_down(s2, off);
        s1 += __shfl_down(s1, off);
    }
    __syncthreads();
    float* red = &ai[0][0];
    const int wave = t >> 6;
    if ((t & 63) == 0) { red[wave * 2] = s2; red[wave * 2 + 1] = s1; }
    __syncthreads();
    if (t == 0) {
        const int bid = (dc * 8 + ti) * 8 + tj;
        ws[SOFF + bid]       = red[0] + red[2] + red[4] + red[6];
        ws[SOFF + 512 + bid] = red[1] + red[3] + red[5] + red[7];
    }
}

__global__ __launch_bounds__(256) void k_mmd(const float* __restrict__ ws,
                                             float* __restrict__ out)
{
    const int t = threadIdx.x;
    __shared__ float sred[8];

    // ---- reduce 512+512 block partials to S2, S1 ----
    float sp2 = ws[SOFF + t] + ws[SOFF + 256 + t];
    float sp1 = ws[SOFF + 512 + t] + ws[SOFF + 768 + t];
#pragma unroll
    for (int off = 32; off > 0; off >>= 1) {
        sp2 += __shfl_down(sp2, off);
        sp1 += __shfl_down(sp1, off);
    }
    if ((t & 63) == 0) { sred[(t >> 6) * 2] = sp2; sred[(t >> 6) * 2 + 1] = sp1; }
    __syncthreads();
    const float S2 = sred[0] + sred[2] + sred[4] + sred[6];
    const float S1 = sred[1] + sred[3] + sred[5] + sred[7];
    // bw = S/(N^2-N)/100 ; factor_t = (N^2-N)*100/S * 0.1^t
    const float r2 = 26163200.0f / S2;   // 512*511*100
    const float r1 = 26163200.0f / S1;

    // ---- two adjacent pairs per thread via dwordx2 loads ----
    const int p0 = (blockIdx.x * 256 + t) * 2;        // even pair index, 512 blocks x 512 pairs
    const unsigned int* partr = (const unsigned int*)ws;

    float l2a = 0.f, l1a = 0.f, l2b = 0.f, l1b = 0.f;
#pragma unroll
    for (int c = 0; c < NCHUNK; ++c) {
        const uint2 w2 = *(const uint2*)&partr[(size_t)c * NN + p0];
        union { unsigned int u; __half2 h; } ca, cb;
        ca.u = w2.x; cb.u = w2.y;
        const float2 fa = __half22float2(ca.h);
        const float2 fb = __half22float2(cb.h);
        l2a += fa.x; l1a += fa.y;
        l2b += fb.x; l1b += fb.y;
    }

    float kv = 0.f;
    {
        float f2 = r2, f1 = r1;
#pragma unroll
        for (int tt = 0; tt < 5; ++tt) {
            kv += __expf(-l2a * f2) + __expf(-l1a * f1)
                + __expf(-l2b * f2) + __expf(-l1b * f1);
            f2 *= 0.1f;
            f1 *= 0.1f;
        }
    }
    // sign uniform across the pair (p0 even -> bit 8 of j identical)
    const int i = p0 >> 9;
    const int j = p0 & 511;
    float acc = ((((i ^ j) & BHALF) == 0) ? kv : -kv);

#pragma unroll
    for (int off = 32; off > 0; off >>= 1) acc += __shfl_down(acc, off);

    __syncthreads();
    if ((t & 63) == 0) sred[t >> 6] = acc;
    __syncthreads();
    if (t == 0) {
        const float s = sred[0] + sred[1] + sred[2] + sred[3];
        atomicAdd(out, s * (1.0f / 65536.0f));
    }
}

extern "C" void kernel_launch(void* const* d_in, const int* in_sizes, int n_in,
                              void* d_out, int out_size, void* d_ws, size_t ws_size,
                              hipStream_t stream)
{
    const float* src = (const float*)d_in[0];
    const float* tgt = (const float*)d_in[1];
    float* ws  = (float*)d_ws;
    float* out = (float*)d_out;

    dim3 g1(8, 8, 8);
    k_dist<<<g1, 256, 0, stream>>>(src, tgt, ws, out);
    k_mmd<<<512, 256, 0, stream>>>(ws, out);
}